// Round 6
// baseline (441.311 us; speedup 1.0000x reference)
//
#include <hip/hip_runtime.h>

#define D 64
#define KC 512
#define EMA_A 0.01f
#define SCHUNK 1024   // rows per segsum chunk
#define NCHUNK 256    // N / SCHUNK
#define BAND 0.03125f // recheck band in he-units (~24x worst-case approx error)

typedef float f32x4 __attribute__((ext_vector_type(4)));
typedef float v4f __attribute__((ext_vector_type(4)));
typedef short s8v __attribute__((ext_vector_type(8)));   // 8 bf16 as shorts
typedef short s4v __attribute__((ext_vector_type(4)));

__device__ inline unsigned short bf16_rne(float f) {
    unsigned u = __float_as_uint(f);
    return (unsigned short)((u + 0x7fffu + ((u >> 16) & 1u)) >> 16);
}
__device__ inline float bf16_f(unsigned short h) {
    return __uint_as_float(((unsigned)h) << 16);
}

// ---- K0: he[k] = 0.5*||emb_k||^2 ; also zeroes the recheck worklist count ----
__global__ __launch_bounds__(256) void k_prep(const float* __restrict__ emb,
                                              float* __restrict__ he,
                                              int* __restrict__ wcount) {
    if (blockIdx.x == 0 && threadIdx.x == 0) wcount[0] = 0;
    int k = blockIdx.x * 256 + threadIdx.x;
    if (k >= KC) return;
    float s = 0.f;
#pragma unroll
    for (int d = 0; d < D; ++d) { float e = emb[k * D + d]; s = fmaf(e, e, s); }
    he[k] = 0.5f * s;
}

// ---- K1: MFMA split-bf16 argmin. Block=256thr(4 waves), 128 rows x all 512
// cols. dot = hh+hl+lh (6 mfma into one fp32 acc). Tracks (min1,idx1,min2);
// rows with min2-min1 < BAND are appended to the recheck worklist.
__global__ __launch_bounds__(256, 3) void k_assign(
    const float* __restrict__ x, const float* __restrict__ emb,
    const float* __restrict__ he, int* __restrict__ idx,
    int* __restrict__ wlist, int* __restrict__ wcount) {
    __shared__ __align__(16) short Ahi[128 * 64];
    __shared__ __align__(16) short Alo[128 * 64];
    __shared__ __align__(16) short Bhi[64 * 64];
    __shared__ __align__(16) short Blo[64 * 64];
    int tid = threadIdx.x;
    int lane = tid & 63, w = tid >> 6, q = lane >> 4, c16 = lane & 15;
    size_t R0 = (size_t)blockIdx.x * 128;

    // stage A: fp32 x tile -> hi/lo bf16, swizzle block kb^=(row&7)
    const float4* xg = (const float4*)(x + R0 * D);
#pragma unroll
    for (int p = 0; p < 8; ++p) {
        int flat = p * 256 + tid;
        int row = flat >> 4, kq = flat & 15;
        float4 v = xg[flat];
        unsigned short h0 = bf16_rne(v.x), h1 = bf16_rne(v.y);
        unsigned short h2 = bf16_rne(v.z), h3 = bf16_rne(v.w);
        s4v hv = {(short)h0, (short)h1, (short)h2, (short)h3};
        s4v lv = {(short)bf16_rne(v.x - bf16_f(h0)),
                  (short)bf16_rne(v.y - bf16_f(h1)),
                  (short)bf16_rne(v.z - bf16_f(h2)),
                  (short)bf16_rne(v.w - bf16_f(h3))};
        int si = row * 64 + (((kq >> 1) ^ (row & 7)) * 8) + (kq & 1) * 4;
        *(s4v*)(&Ahi[si]) = hv;
        *(s4v*)(&Alo[si]) = lv;
    }
    __syncthreads();

    // A fragments held in regs for the whole kernel (8 frags = 32 VGPR)
    s8v ah[2][2], al[2][2];
#pragma unroll
    for (int rt = 0; rt < 2; ++rt)
#pragma unroll
        for (int ks = 0; ks < 2; ++ks) {
            int row = w * 32 + rt * 16 + c16;
            int kb = (ks * 4 + q) ^ (row & 7);
            ah[rt][ks] = *(const s8v*)(&Ahi[row * 64 + kb * 8]);
            al[rt][ks] = *(const s8v*)(&Alo[row * 64 + kb * 8]);
        }

    float m1[8], m2[8]; int i1[8];
#pragma unroll
    for (int e = 0; e < 8; ++e) { m1[e] = 3.4e38f; m2[e] = 3.4e38f; i1[e] = 0; }

    for (int c8 = 0; c8 < 8; ++c8) {
        if (c8) __syncthreads();
        const float4* eg = (const float4*)(emb + (size_t)c8 * 64 * D);
#pragma unroll
        for (int p = 0; p < 4; ++p) {
            int flat = p * 256 + tid;
            int c = flat >> 4, kq = flat & 15;
            float4 v = eg[flat];
            unsigned short h0 = bf16_rne(v.x), h1 = bf16_rne(v.y);
            unsigned short h2 = bf16_rne(v.z), h3 = bf16_rne(v.w);
            s4v hv = {(short)h0, (short)h1, (short)h2, (short)h3};
            s4v lv = {(short)bf16_rne(v.x - bf16_f(h0)),
                      (short)bf16_rne(v.y - bf16_f(h1)),
                      (short)bf16_rne(v.z - bf16_f(h2)),
                      (short)bf16_rne(v.w - bf16_f(h3))};
            int si = c * 64 + (((kq >> 1) ^ (c & 7)) * 8) + (kq & 1) * 4;
            *(s4v*)(&Bhi[si]) = hv;
            *(s4v*)(&Blo[si]) = lv;
        }
        __syncthreads();
#pragma unroll
        for (int ct = 0; ct < 4; ++ct) {
            s8v bh[2], bl[2];
#pragma unroll
            for (int ks = 0; ks < 2; ++ks) {
                int c = ct * 16 + c16;
                int kb = (ks * 4 + q) ^ (c & 7);
                bh[ks] = *(const s8v*)(&Bhi[c * 64 + kb * 8]);
                bl[ks] = *(const s8v*)(&Blo[c * 64 + kb * 8]);
            }
            int cbase = c8 * 64 + ct * 16;
            float hec = he[cbase + c16];
            int ci = cbase + c16;
#pragma unroll
            for (int rt = 0; rt < 2; ++rt) {
                f32x4 acc = {0.f, 0.f, 0.f, 0.f};
                acc = __builtin_amdgcn_mfma_f32_16x16x32_bf16(ah[rt][0], bh[0], acc, 0, 0, 0);
                acc = __builtin_amdgcn_mfma_f32_16x16x32_bf16(ah[rt][1], bh[1], acc, 0, 0, 0);
                acc = __builtin_amdgcn_mfma_f32_16x16x32_bf16(ah[rt][0], bl[0], acc, 0, 0, 0);
                acc = __builtin_amdgcn_mfma_f32_16x16x32_bf16(ah[rt][1], bl[1], acc, 0, 0, 0);
                acc = __builtin_amdgcn_mfma_f32_16x16x32_bf16(al[rt][0], bh[0], acc, 0, 0, 0);
                acc = __builtin_amdgcn_mfma_f32_16x16x32_bf16(al[rt][1], bh[1], acc, 0, 0, 0);
#pragma unroll
                for (int r = 0; r < 4; ++r) {
                    float d = hec - acc[r];
                    int e = rt * 4 + r;
                    m2[e] = fminf(m2[e], fmaxf(d, m1[e]));  // before m1 update
                    bool lt = d < m1[e];                    // strict: first-min
                    i1[e] = lt ? ci : i1[e];
                    m1[e] = fminf(m1[e], d);
                }
            }
        }
    }
    // reduce (m1,i1,m2) across the 16 lanes of each quad group
#pragma unroll
    for (int m = 1; m < 16; m <<= 1) {
#pragma unroll
        for (int e = 0; e < 8; ++e) {
            float om1 = __shfl_xor(m1[e], m);
            float om2 = __shfl_xor(m2[e], m);
            int oi = __shfl_xor(i1[e], m);
            float nm2 = fminf(fminf(m2[e], om2), fmaxf(m1[e], om1));
            bool take = (om1 < m1[e]) || (om1 == m1[e] && oi < i1[e]);
            i1[e] = take ? oi : i1[e];
            m1[e] = fminf(m1[e], om1);
            m2[e] = nm2;
        }
    }
    if (c16 == 0) {
#pragma unroll
        for (int e = 0; e < 8; ++e) {
            int row = (int)R0 + w * 32 + (e >> 2) * 16 + q * 4 + (e & 3);
            idx[row] = i1[e];
            if (m2[e] - m1[e] < BAND) {       // ambiguous under approx error
                int pos = atomicAdd(wcount, 1);
                wlist[pos] = row;
            }
        }
    }
}

// ---- K1b: exact fp32 rescan, one WAVE per worklist row, grid-stride ----
__global__ __launch_bounds__(256) void k_recheck(
    const float* __restrict__ x, const float* __restrict__ emb,
    const float* __restrict__ he, const int* __restrict__ wlist,
    const int* __restrict__ wcount, int* __restrict__ idx) {
    int lane = threadIdx.x & 63;
    int wave = (blockIdx.x * 256 + threadIdx.x) >> 6;
    int nwaves = (gridDim.x * 256) >> 6;
    int cnt = wcount[0];
    for (int i = wave; i < cnt; i += nwaves) {
        int row = wlist[i];
        const v4f* xr = (const v4f*)(x + (size_t)row * D);
        v4f X[16];
#pragma unroll
        for (int t = 0; t < 16; ++t) X[t] = xr[t];   // broadcast (same addr)
        float bd = 3.4e38f; int bi = 0x7fffffff;
#pragma unroll
        for (int j = 0; j < 8; ++j) {
            int c = j * 64 + lane;
            const v4f* er = (const v4f*)(emb + (size_t)c * D);
            v4f s = X[0] * er[0];
#pragma unroll
            for (int t = 1; t < 16; ++t) s += X[t] * er[t];
            float dot = (s.x + s.y) + (s.z + s.w);
            float d = he[c] - dot;
            if (d < bd) { bd = d; bi = c; }  // c ascending per lane
        }
#pragma unroll
        for (int m = 1; m < 64; m <<= 1) {
            float od = __shfl_xor(bd, m);
            int oi = __shfl_xor(bi, m);
            if (od < bd || (od == bd && oi < bi)) { bd = od; bi = oi; }
        }
        if (lane == 0) idx[row] = bi;
    }
}

// ---- K2a: per-block histogram ----
__global__ __launch_bounds__(256) void k_hist(const int* __restrict__ idx,
                                              float* __restrict__ gcount) {
    __shared__ int hist[KC];
    int tid = threadIdx.x;
    for (int i = tid; i < KC; i += 256) hist[i] = 0;
    __syncthreads();
    atomicAdd(&hist[idx[blockIdx.x * 256 + tid]], 1);
    __syncthreads();
    for (int i = tid; i < KC; i += 256)
        gcount[(size_t)blockIdx.x * KC + i] = (float)hist[i];
}

// ---- K2b: LDS-privatized segment sums; k-halves split across blocks ----
__global__ __launch_bounds__(512) void k_segsum(
    const float* __restrict__ x, const int* __restrict__ idx,
    float* __restrict__ gpart, int N) {
    __shared__ float part[256 * D];  // 64 KB
    int tid = threadIdx.x;
    int chunk = blockIdx.x >> 1;
    int half = blockIdx.x & 1;
    int base = chunk * SCHUNK;
    int end = base + SCHUNK; if (end > N) end = N;
    for (int i = tid; i < 256 * D; i += 512) part[i] = 0.f;
    __syncthreads();
    for (int r = base + tid; r < end; r += 512) {
        int k = idx[r];
        if ((k >> 8) == half) {
            int kl = k & 255;
            const float4* p = (const float4*)(x + (size_t)r * D);
#pragma unroll
            for (int i = 0; i < D / 4; ++i) {
                float4 v = p[i];
                int d = 4 * i;
                atomicAdd(&part[kl * D + ((d + 0 + kl) & 63)], v.x);
                atomicAdd(&part[kl * D + ((d + 1 + kl) & 63)], v.y);
                atomicAdd(&part[kl * D + ((d + 2 + kl) & 63)], v.z);
                atomicAdd(&part[kl * D + ((d + 3 + kl) & 63)], v.w);
            }
        }
    }
    __syncthreads();
    size_t ob = (size_t)chunk * (KC * D) + (size_t)half * (256 * D);
    for (int i = tid; i < 256 * D; i += 512) {
        int kl = i >> 6, d = i & 63;
        gpart[ob + i] = part[kl * D + ((d + kl) & 63)];
    }
}

// ---- K3a: stage-1 reduce of gpart over chunks: 4 groups of 64 ----
__global__ __launch_bounds__(256) void k_sumred(const float* __restrict__ gpart,
                                                float* __restrict__ spart) {
    int b = blockIdx.x;
    int g = b >> 7;
    int i = (b & 127) * 256 + threadIdx.x;
    float s = 0.f;
    for (int c = g * 64; c < g * 64 + 64; ++c)
        s += gpart[(size_t)c * (KC * D) + i];
    spart[(size_t)g * (KC * D) + i] = s;
}

// ---- K3b: reduce gcount over 1024 partials: 8 groups of 128 ----
__global__ __launch_bounds__(256) void k_cred(const float* __restrict__ gcount,
                                              float* __restrict__ cpart) {
    int gid = blockIdx.x * 256 + threadIdx.x;
    int g = gid >> 9;
    int k = gid & 511;
    float s = 0.f;
    for (int b = g * 128; b < g * 128 + 128; ++b)
        s += gcount[(size_t)b * KC + k];
    cpart[gid] = s;
}

// ---- K4: finish reductions + EMA -> embedding_new ----
// usage==0 clusters never appear in encoding_index -> flat[r] path is dead.
__global__ __launch_bounds__(256) void k_embnew(
    const float* __restrict__ spart, const float* __restrict__ cpart,
    const float* __restrict__ cnt_in, const float* __restrict__ sum_embed,
    float* __restrict__ embnew) {
    int i = blockIdx.x * 256 + threadIdx.x;
    int k = i >> 6;
    float s = spart[i] + spart[(size_t)1 * (KC * D) + i] +
              spart[(size_t)2 * (KC * D) + i] + spart[(size_t)3 * (KC * D) + i];
    float c = 0.f;
#pragma unroll
    for (int g = 0; g < 8; ++g) c += cpart[g * KC + k];
    float c0 = cnt_in[k];
    float cn = c0 + EMA_A * (c - c0);
    float se0 = sum_embed[i];
    float se = se0 + EMA_A * (s - se0);
    embnew[i] = (cn >= 1.0f) ? (se / cn) : 0.0f;
}

// ---- K5: gather ----
__global__ __launch_bounds__(256) void k_gather(const int* __restrict__ idx,
                                                const float* __restrict__ embnew,
                                                float* __restrict__ out, int N) {
    int g = blockIdx.x * 256 + threadIdx.x;
    int row = g >> 4, q = g & 15;
    if (row >= N) return;
    int k = idx[row];
    const float4* e4 = (const float4*)embnew;
    ((float4*)out)[(size_t)row * (D / 4) + q] = e4[k * (D / 4) + q];
}

extern "C" void kernel_launch(void* const* d_in, const int* in_sizes, int n_in,
                              void* d_out, int out_size, void* d_ws, size_t ws_size,
                              hipStream_t stream) {
    const float* x = (const float*)d_in[0];
    const float* emb = (const float*)d_in[1];
    const float* cnt = (const float*)d_in[2];
    const float* sum_embed = (const float*)d_in[3];
    float* out = (float*)d_out;
    int N = in_sizes[0] / D;  // 262144
    int hblk = N / 256;       // 1024

    char* w = (char*)d_ws;
    size_t off = 0;
    int* idx = (int*)(w + off);        off += (size_t)N * 4;
    int* wlist = (int*)(w + off);      off += (size_t)N * 4;
    int* wcount = (int*)(w + off);     off += 16;
    float* he = (float*)(w + off);     off += (size_t)KC * 4;
    float* embnew = (float*)(w + off); off += (size_t)KC * D * 4;
    float* gcount = (float*)(w + off); off += (size_t)hblk * KC * 4;
    float* cpart = (float*)(w + off);  off += (size_t)8 * KC * 4;
    float* spart = (float*)(w + off);  off += (size_t)4 * KC * D * 4;
    float* gpart = (float*)(w + off);  off += (size_t)NCHUNK * KC * D * 4;

    k_prep<<<(KC + 255) / 256, 256, 0, stream>>>(emb, he, wcount);
    k_assign<<<N / 128, 256, 0, stream>>>(x, emb, he, idx, wlist, wcount);
    k_recheck<<<512, 256, 0, stream>>>(x, emb, he, wlist, wcount, idx);
    k_hist<<<hblk, 256, 0, stream>>>(idx, gcount);
    k_segsum<<<NCHUNK * 2, 512, 0, stream>>>(x, idx, gpart, N);
    k_sumred<<<512, 256, 0, stream>>>(gpart, spart);
    k_cred<<<16, 256, 0, stream>>>(gcount, cpart);
    k_embnew<<<(KC * D) / 256, 256, 0, stream>>>(spart, cpart, cnt, sum_embed, embnew);
    k_gather<<<((size_t)N * (D / 4)) / 256, 256, 0, stream>>>(idx, embnew, out, N);
}

// Round 7
// 363.875 us; speedup vs baseline: 1.2128x; 1.2128x over previous
//
#include <hip/hip_runtime.h>

#define D 64
#define KC 512
#define EMA_A 0.01f
#define SCHUNK 1024    // rows per segsum chunk
#define NCHUNK 256     // N / SCHUNK
#define HROWS 1024     // rows per hist block
#define NHB 256        // N / HROWS
#define BAND 0.0078125f // recheck band; 4-term split error <~5e-4 -> 16x margin

typedef float f32x4 __attribute__((ext_vector_type(4)));
typedef float v4f __attribute__((ext_vector_type(4)));
typedef short s8v __attribute__((ext_vector_type(8)));   // 8 bf16 as shorts
typedef short s4v __attribute__((ext_vector_type(4)));

__device__ inline unsigned short bf16_rne(float f) {
    unsigned u = __float_as_uint(f);
    return (unsigned short)((u + 0x7fffu + ((u >> 16) & 1u)) >> 16);
}
__device__ inline float bf16_f(unsigned short h) {
    return __uint_as_float(((unsigned)h) << 16);
}

// ---- K0: he[k] = 0.5*||emb_k||^2 ; pre-swizzled bf16 hi/lo B images ;
//          zero recheck worklist count ----
// gB layout per 64-col chunk c8 (8192 shorts = 16KB, exact LDS image):
//   [0..4095]=hi, [4096..8191]=lo, si = c*64 + ((kq>>1)^(c&7))*8 + (kq&1)*4
__global__ __launch_bounds__(256) void k_prep(const float* __restrict__ emb,
                                              float* __restrict__ he,
                                              short* __restrict__ gB,
                                              int* __restrict__ wcount) {
    if (blockIdx.x == 0 && threadIdx.x == 0) wcount[0] = 0;
    int k = blockIdx.x * 256 + threadIdx.x;
    if (k >= KC) return;
    int c8 = k >> 6, c = k & 63;
    short* dst = gB + (size_t)c8 * 8192;
    float s = 0.f;
#pragma unroll
    for (int kq = 0; kq < 16; ++kq) {
        float4 v = ((const float4*)(emb + (size_t)k * D))[kq];
        s = fmaf(v.x, v.x, s); s = fmaf(v.y, v.y, s);
        s = fmaf(v.z, v.z, s); s = fmaf(v.w, v.w, s);
        unsigned short h0 = bf16_rne(v.x), h1 = bf16_rne(v.y);
        unsigned short h2 = bf16_rne(v.z), h3 = bf16_rne(v.w);
        s4v hv = {(short)h0, (short)h1, (short)h2, (short)h3};
        s4v lv = {(short)bf16_rne(v.x - bf16_f(h0)),
                  (short)bf16_rne(v.y - bf16_f(h1)),
                  (short)bf16_rne(v.z - bf16_f(h2)),
                  (short)bf16_rne(v.w - bf16_f(h3))};
        int si = c * 64 + (((kq >> 1) ^ (c & 7)) * 8) + (kq & 1) * 4;
        *(s4v*)(&dst[si]) = hv;
        *(s4v*)(&dst[4096 + si]) = lv;
    }
    he[k] = 0.5f * s;
}

// ---- K1: MFMA 4-term split-bf16 argmin. 128 rows x 512 cols per block.
// LDS: 2x16KB double buffer. A hi->LB[0], lo->LB[1] staged first; A frags
// -> regs; then B chunks (pre-converted) cycle through the buffers.
// dot = hh+hl+lh+ll (8 mfma, fp32 acc). 11 barriers vs 17.
__global__ __launch_bounds__(256, 4) void k_assign(
    const float* __restrict__ x, const short* __restrict__ gB,
    const float* __restrict__ he, int* __restrict__ idx,
    int* __restrict__ wlist, int* __restrict__ wcount) {
    __shared__ __align__(16) short LB[2][8192];  // 32 KB
    __shared__ int wl_cnt, wl_base;
    __shared__ int wl_rows[128];
    int tid = threadIdx.x;
    int lane = tid & 63, w = tid >> 6, q = lane >> 4, c16 = lane & 15;
    size_t R0 = (size_t)blockIdx.x * 128;
    if (tid == 0) wl_cnt = 0;

    // stage A: fp32 x tile -> hi/lo bf16 LDS images
    const float4* xg = (const float4*)(x + R0 * D);
#pragma unroll
    for (int p = 0; p < 8; ++p) {
        int flat = p * 256 + tid;
        int row = flat >> 4, kq = flat & 15;
        float4 v = xg[flat];
        unsigned short h0 = bf16_rne(v.x), h1 = bf16_rne(v.y);
        unsigned short h2 = bf16_rne(v.z), h3 = bf16_rne(v.w);
        s4v hv = {(short)h0, (short)h1, (short)h2, (short)h3};
        s4v lv = {(short)bf16_rne(v.x - bf16_f(h0)),
                  (short)bf16_rne(v.y - bf16_f(h1)),
                  (short)bf16_rne(v.z - bf16_f(h2)),
                  (short)bf16_rne(v.w - bf16_f(h3))};
        int si = row * 64 + (((kq >> 1) ^ (row & 7)) * 8) + (kq & 1) * 4;
        *(s4v*)(&LB[0][si]) = hv;
        *(s4v*)(&LB[1][si]) = lv;
    }
    __syncthreads();

    // A fragments -> regs for the whole kernel (16 frags = 64 VGPR)
    s8v ah[2][2], al[2][2];
#pragma unroll
    for (int rt = 0; rt < 2; ++rt)
#pragma unroll
        for (int ks = 0; ks < 2; ++ks) {
            int row = w * 32 + rt * 16 + c16;
            int kb = (ks * 4 + q) ^ (row & 7);
            ah[rt][ks] = *(const s8v*)(&LB[0][row * 64 + kb * 8]);
            al[rt][ks] = *(const s8v*)(&LB[1][row * 64 + kb * 8]);
        }
    __syncthreads();  // all waves done reading A -> buffers reusable

    // stage B chunk 0 (pure 16B copies of pre-converted image)
#pragma unroll
    for (int p = 0; p < 4; ++p)
        ((int4*)LB[0])[p * 256 + tid] = ((const int4*)gB)[p * 256 + tid];
    __syncthreads();

    float m1[8], m2[8]; int i1[8];
#pragma unroll
    for (int e = 0; e < 8; ++e) { m1[e] = 3.4e38f; m2[e] = 3.4e38f; i1[e] = 0; }

    for (int c8 = 0; c8 < 8; ++c8) {
        if (c8 < 7) {  // prefetch next chunk into the other buffer
            const int4* src = (const int4*)(gB + (size_t)(c8 + 1) * 8192);
            int4* dst = (int4*)LB[(c8 + 1) & 1];
#pragma unroll
            for (int p = 0; p < 4; ++p)
                dst[p * 256 + tid] = src[p * 256 + tid];
        }
        const short* LBc = LB[c8 & 1];
#pragma unroll
        for (int ct = 0; ct < 4; ++ct) {
            s8v bh[2], bl[2];
#pragma unroll
            for (int ks = 0; ks < 2; ++ks) {
                int c = ct * 16 + c16;
                int kb = (ks * 4 + q) ^ (c & 7);
                bh[ks] = *(const s8v*)(&LBc[c * 64 + kb * 8]);
                bl[ks] = *(const s8v*)(&LBc[4096 + c * 64 + kb * 8]);
            }
            int cbase = c8 * 64 + ct * 16;
            float hec = he[cbase + c16];
            int ci = cbase + c16;
#pragma unroll
            for (int rt = 0; rt < 2; ++rt) {
                f32x4 acc = {0.f, 0.f, 0.f, 0.f};
                acc = __builtin_amdgcn_mfma_f32_16x16x32_bf16(ah[rt][0], bh[0], acc, 0, 0, 0);
                acc = __builtin_amdgcn_mfma_f32_16x16x32_bf16(ah[rt][1], bh[1], acc, 0, 0, 0);
                acc = __builtin_amdgcn_mfma_f32_16x16x32_bf16(ah[rt][0], bl[0], acc, 0, 0, 0);
                acc = __builtin_amdgcn_mfma_f32_16x16x32_bf16(ah[rt][1], bl[1], acc, 0, 0, 0);
                acc = __builtin_amdgcn_mfma_f32_16x16x32_bf16(al[rt][0], bh[0], acc, 0, 0, 0);
                acc = __builtin_amdgcn_mfma_f32_16x16x32_bf16(al[rt][1], bh[1], acc, 0, 0, 0);
                acc = __builtin_amdgcn_mfma_f32_16x16x32_bf16(al[rt][0], bl[0], acc, 0, 0, 0);
                acc = __builtin_amdgcn_mfma_f32_16x16x32_bf16(al[rt][1], bl[1], acc, 0, 0, 0);
#pragma unroll
                for (int r = 0; r < 4; ++r) {
                    float d = hec - acc[r];
                    int e = rt * 4 + r;
                    m2[e] = fminf(m2[e], fmaxf(d, m1[e]));  // before m1 update
                    bool lt = d < m1[e];                    // strict: first-min
                    i1[e] = lt ? ci : i1[e];
                    m1[e] = fminf(m1[e], d);
                }
            }
        }
        __syncthreads();
    }
    // reduce (m1,i1,m2) across the 16 lanes of each quad group
#pragma unroll
    for (int m = 1; m < 16; m <<= 1) {
#pragma unroll
        for (int e = 0; e < 8; ++e) {
            float om1 = __shfl_xor(m1[e], m);
            float om2 = __shfl_xor(m2[e], m);
            int oi = __shfl_xor(i1[e], m);
            float nm2 = fminf(fminf(m2[e], om2), fmaxf(m1[e], om1));
            bool take = (om1 < m1[e]) || (om1 == m1[e] && oi < i1[e]);
            i1[e] = take ? oi : i1[e];
            m1[e] = fminf(m1[e], om1);
            m2[e] = nm2;
        }
    }
    if (c16 == 0) {
#pragma unroll
        for (int e = 0; e < 8; ++e) {
            int row = (int)R0 + w * 32 + (e >> 2) * 16 + q * 4 + (e & 3);
            idx[row] = i1[e];
            if (m2[e] - m1[e] < BAND) {       // ambiguous under approx error
                int p = atomicAdd(&wl_cnt, 1);   // LDS atomic
                wl_rows[p] = row;
            }
        }
    }
    __syncthreads();
    if (tid == 0 && wl_cnt > 0) wl_base = atomicAdd(wcount, wl_cnt);
    __syncthreads();
    for (int i = tid; i < wl_cnt; i += 256) wlist[wl_base + i] = wl_rows[i];
}

// ---- K1b: exact fp32 rescan, one WAVE per worklist row, grid-stride ----
__global__ __launch_bounds__(256) void k_recheck(
    const float* __restrict__ x, const float* __restrict__ emb,
    const float* __restrict__ he, const int* __restrict__ wlist,
    const int* __restrict__ wcount, int* __restrict__ idx) {
    int lane = threadIdx.x & 63;
    int wave = (blockIdx.x * 256 + threadIdx.x) >> 6;
    int nwaves = (gridDim.x * 256) >> 6;
    int cnt = wcount[0];
    for (int i = wave; i < cnt; i += nwaves) {
        int row = wlist[i];
        const v4f* xr = (const v4f*)(x + (size_t)row * D);
        v4f X[16];
#pragma unroll
        for (int t = 0; t < 16; ++t) X[t] = xr[t];   // broadcast (same addr)
        float bd = 3.4e38f; int bi = 0x7fffffff;
#pragma unroll
        for (int j = 0; j < 8; ++j) {
            int c = j * 64 + lane;
            const v4f* er = (const v4f*)(emb + (size_t)c * D);
            v4f s = X[0] * er[0];
#pragma unroll
            for (int t = 1; t < 16; ++t) s += X[t] * er[t];
            float dot = (s.x + s.y) + (s.z + s.w);
            float d = he[c] - dot;
            if (d < bd) { bd = d; bi = c; }  // c ascending per lane
        }
#pragma unroll
        for (int m = 1; m < 64; m <<= 1) {
            float od = __shfl_xor(bd, m);
            int oi = __shfl_xor(bi, m);
            if (od < bd || (od == bd && oi < bi)) { bd = od; bi = oi; }
        }
        if (lane == 0) idx[row] = bi;
    }
}

// ---- K2a: per-block histogram (256 partials of KC) ----
__global__ __launch_bounds__(256) void k_hist(const int* __restrict__ idx,
                                              float* __restrict__ gcount) {
    __shared__ int hist[KC];
    int tid = threadIdx.x;
    for (int i = tid; i < KC; i += 256) hist[i] = 0;
    __syncthreads();
    int base = blockIdx.x * HROWS;
    for (int r = base + tid; r < base + HROWS; r += 256)
        atomicAdd(&hist[idx[r]], 1);
    __syncthreads();
    for (int i = tid; i < KC; i += 256)
        gcount[(size_t)blockIdx.x * KC + i] = (float)hist[i];
}

// ---- K2b: LDS-privatized segment sums; k-halves split across blocks ----
__global__ __launch_bounds__(512) void k_segsum(
    const float* __restrict__ x, const int* __restrict__ idx,
    float* __restrict__ gpart, int N) {
    __shared__ float part[256 * D];  // 64 KB
    int tid = threadIdx.x;
    int chunk = blockIdx.x >> 1;
    int half = blockIdx.x & 1;
    int base = chunk * SCHUNK;
    int end = base + SCHUNK; if (end > N) end = N;
    for (int i = tid; i < 256 * D; i += 512) part[i] = 0.f;
    __syncthreads();
    for (int r = base + tid; r < end; r += 512) {
        int k = idx[r];
        if ((k >> 8) == half) {
            int kl = k & 255;
            const float4* p = (const float4*)(x + (size_t)r * D);
#pragma unroll
            for (int i = 0; i < D / 4; ++i) {
                float4 v = p[i];
                int d = 4 * i;
                atomicAdd(&part[kl * D + ((d + 0 + kl) & 63)], v.x);
                atomicAdd(&part[kl * D + ((d + 1 + kl) & 63)], v.y);
                atomicAdd(&part[kl * D + ((d + 2 + kl) & 63)], v.z);
                atomicAdd(&part[kl * D + ((d + 3 + kl) & 63)], v.w);
            }
        }
    }
    __syncthreads();
    size_t ob = (size_t)chunk * (KC * D) + (size_t)half * (256 * D);
    for (int i = tid; i < 256 * D; i += 512) {
        int kl = i >> 6, d = i & 63;
        gpart[ob + i] = part[kl * D + ((d + kl) & 63)];
    }
}

// ---- K3: fused reduce(gpart) + reduce(gcount) + EMA -> embedding_new ----
// usage==0 clusters never appear in encoding_index -> flat[r] path is dead.
__global__ __launch_bounds__(256) void k_final(
    const float* __restrict__ gpart, const float* __restrict__ gcount,
    const float* __restrict__ cnt_in, const float* __restrict__ sum_embed,
    float* __restrict__ embnew) {
    __shared__ float cs[4];
    int tid = threadIdx.x;
    int i = blockIdx.x * 256 + tid;   // < KC*D = 32768
    float s = 0.f;
#pragma unroll 4
    for (int c = 0; c < NCHUNK; ++c) s += gpart[(size_t)c * (KC * D) + i];
    if ((tid & 63) == 0) {
        int k = i >> 6;
        float c = 0.f;
#pragma unroll 4
        for (int b = 0; b < NHB; ++b) c += gcount[(size_t)b * KC + k];
        cs[tid >> 6] = c;
    }
    __syncthreads();
    float c = cs[tid >> 6];
    float c0 = cnt_in[i >> 6];
    float cn = c0 + EMA_A * (c - c0);
    float se0 = sum_embed[i];
    float se = se0 + EMA_A * (s - se0);
    embnew[i] = (cn >= 1.0f) ? (se / cn) : 0.0f;
}

// ---- K4: gather out[n][:] = embnew[idx[n]][:] ----
__global__ __launch_bounds__(256) void k_gather(const int* __restrict__ idx,
                                                const float* __restrict__ embnew,
                                                float* __restrict__ out, int N) {
    int g = blockIdx.x * 256 + threadIdx.x;
    int row = g >> 4, q = g & 15;
    if (row >= N) return;
    int k = idx[row];
    const float4* e4 = (const float4*)embnew;
    ((float4*)out)[(size_t)row * (D / 4) + q] = e4[k * (D / 4) + q];
}

extern "C" void kernel_launch(void* const* d_in, const int* in_sizes, int n_in,
                              void* d_out, int out_size, void* d_ws, size_t ws_size,
                              hipStream_t stream) {
    const float* x = (const float*)d_in[0];
    const float* emb = (const float*)d_in[1];
    const float* cnt = (const float*)d_in[2];
    const float* sum_embed = (const float*)d_in[3];
    float* out = (float*)d_out;
    int N = in_sizes[0] / D;  // 262144

    char* w = (char*)d_ws;
    size_t off = 0;
    int* idx = (int*)(w + off);        off += (size_t)N * 4;
    int* wlist = (int*)(w + off);      off += (size_t)N * 4;
    int* wcount = (int*)(w + off);     off += 16;
    float* he = (float*)(w + off);     off += (size_t)KC * 4;
    short* gB = (short*)(w + off);     off += (size_t)8 * 8192 * 2;  // 128 KB
    float* embnew = (float*)(w + off); off += (size_t)KC * D * 4;
    float* gcount = (float*)(w + off); off += (size_t)NHB * KC * 4;
    float* gpart = (float*)(w + off);  off += (size_t)NCHUNK * KC * D * 4;

    k_prep<<<(KC + 255) / 256, 256, 0, stream>>>(emb, he, gB, wcount);
    k_assign<<<N / 128, 256, 0, stream>>>(x, gB, he, idx, wlist, wcount);
    k_recheck<<<512, 256, 0, stream>>>(x, emb, he, wlist, wcount, idx);
    k_hist<<<NHB, 256, 0, stream>>>(idx, gcount);
    k_segsum<<<NCHUNK * 2, 512, 0, stream>>>(x, idx, gpart, N);
    k_final<<<(KC * D) / 256, 256, 0, stream>>>(gpart, gcount, cnt, sum_embed, embnew);
    k_gather<<<((size_t)N * (D / 4)) / 256, 256, 0, stream>>>(idx, embnew, out, N);
}

// Round 8
// 321.128 us; speedup vs baseline: 1.3743x; 1.1331x over previous
//
#include <hip/hip_runtime.h>

#define D 64
#define KC 512
#define EMA_A 0.01f
#define SROWS 1024     // rows per segsum block
#define NCHUNK 256     // N / SROWS (gpart partials)
#define HROWS 1024     // rows per hist block
#define NHB 256        // N / HROWS
#define BAND 0.0078125f // recheck band; 4-term split error <~5e-4 -> 16x margin

typedef float f32x4 __attribute__((ext_vector_type(4)));
typedef float v4f __attribute__((ext_vector_type(4)));
typedef short s8v __attribute__((ext_vector_type(8)));   // 8 bf16 as shorts
typedef short s4v __attribute__((ext_vector_type(4)));

__device__ inline unsigned short bf16_rne(float f) {
    unsigned u = __float_as_uint(f);
    return (unsigned short)((u + 0x7fffu + ((u >> 16) & 1u)) >> 16);
}
__device__ inline float bf16_f(unsigned short h) {
    return __uint_as_float(((unsigned)h) << 16);
}

// ---- K0: he[k] = 0.5*||emb_k||^2 ; pre-swizzled bf16 hi/lo B images ;
//          zero recheck worklist count ----
__global__ __launch_bounds__(256) void k_prep(const float* __restrict__ emb,
                                              float* __restrict__ he,
                                              short* __restrict__ gB,
                                              int* __restrict__ wcount) {
    if (blockIdx.x == 0 && threadIdx.x == 0) wcount[0] = 0;
    int k = blockIdx.x * 256 + threadIdx.x;
    if (k >= KC) return;
    int c8 = k >> 6, c = k & 63;
    short* dst = gB + (size_t)c8 * 8192;
    float s = 0.f;
#pragma unroll
    for (int kq = 0; kq < 16; ++kq) {
        float4 v = ((const float4*)(emb + (size_t)k * D))[kq];
        s = fmaf(v.x, v.x, s); s = fmaf(v.y, v.y, s);
        s = fmaf(v.z, v.z, s); s = fmaf(v.w, v.w, s);
        unsigned short h0 = bf16_rne(v.x), h1 = bf16_rne(v.y);
        unsigned short h2 = bf16_rne(v.z), h3 = bf16_rne(v.w);
        s4v hv = {(short)h0, (short)h1, (short)h2, (short)h3};
        s4v lv = {(short)bf16_rne(v.x - bf16_f(h0)),
                  (short)bf16_rne(v.y - bf16_f(h1)),
                  (short)bf16_rne(v.z - bf16_f(h2)),
                  (short)bf16_rne(v.w - bf16_f(h3))};
        int si = c * 64 + (((kq >> 1) ^ (c & 7)) * 8) + (kq & 1) * 4;
        *(s4v*)(&dst[si]) = hv;
        *(s4v*)(&dst[4096 + si]) = lv;
    }
    he[k] = 0.5f * s;
}

// ---- K1: MFMA 4-term split-bf16 argmin (unchanged from R7) ----
__global__ __launch_bounds__(256, 4) void k_assign(
    const float* __restrict__ x, const short* __restrict__ gB,
    const float* __restrict__ he, int* __restrict__ idx,
    int* __restrict__ wlist, int* __restrict__ wcount) {
    __shared__ __align__(16) short LB[2][8192];  // 32 KB
    __shared__ int wl_cnt, wl_base;
    __shared__ int wl_rows[128];
    int tid = threadIdx.x;
    int lane = tid & 63, w = tid >> 6, q = lane >> 4, c16 = lane & 15;
    size_t R0 = (size_t)blockIdx.x * 128;
    if (tid == 0) wl_cnt = 0;

    const float4* xg = (const float4*)(x + R0 * D);
#pragma unroll
    for (int p = 0; p < 8; ++p) {
        int flat = p * 256 + tid;
        int row = flat >> 4, kq = flat & 15;
        float4 v = xg[flat];
        unsigned short h0 = bf16_rne(v.x), h1 = bf16_rne(v.y);
        unsigned short h2 = bf16_rne(v.z), h3 = bf16_rne(v.w);
        s4v hv = {(short)h0, (short)h1, (short)h2, (short)h3};
        s4v lv = {(short)bf16_rne(v.x - bf16_f(h0)),
                  (short)bf16_rne(v.y - bf16_f(h1)),
                  (short)bf16_rne(v.z - bf16_f(h2)),
                  (short)bf16_rne(v.w - bf16_f(h3))};
        int si = row * 64 + (((kq >> 1) ^ (row & 7)) * 8) + (kq & 1) * 4;
        *(s4v*)(&LB[0][si]) = hv;
        *(s4v*)(&LB[1][si]) = lv;
    }
    __syncthreads();

    s8v ah[2][2], al[2][2];
#pragma unroll
    for (int rt = 0; rt < 2; ++rt)
#pragma unroll
        for (int ks = 0; ks < 2; ++ks) {
            int row = w * 32 + rt * 16 + c16;
            int kb = (ks * 4 + q) ^ (row & 7);
            ah[rt][ks] = *(const s8v*)(&LB[0][row * 64 + kb * 8]);
            al[rt][ks] = *(const s8v*)(&LB[1][row * 64 + kb * 8]);
        }
    __syncthreads();

#pragma unroll
    for (int p = 0; p < 4; ++p)
        ((int4*)LB[0])[p * 256 + tid] = ((const int4*)gB)[p * 256 + tid];
    __syncthreads();

    float m1[8], m2[8]; int i1[8];
#pragma unroll
    for (int e = 0; e < 8; ++e) { m1[e] = 3.4e38f; m2[e] = 3.4e38f; i1[e] = 0; }

    for (int c8 = 0; c8 < 8; ++c8) {
        if (c8 < 7) {
            const int4* src = (const int4*)(gB + (size_t)(c8 + 1) * 8192);
            int4* dst = (int4*)LB[(c8 + 1) & 1];
#pragma unroll
            for (int p = 0; p < 4; ++p)
                dst[p * 256 + tid] = src[p * 256 + tid];
        }
        const short* LBc = LB[c8 & 1];
#pragma unroll
        for (int ct = 0; ct < 4; ++ct) {
            s8v bh[2], bl[2];
#pragma unroll
            for (int ks = 0; ks < 2; ++ks) {
                int c = ct * 16 + c16;
                int kb = (ks * 4 + q) ^ (c & 7);
                bh[ks] = *(const s8v*)(&LBc[c * 64 + kb * 8]);
                bl[ks] = *(const s8v*)(&LBc[4096 + c * 64 + kb * 8]);
            }
            int cbase = c8 * 64 + ct * 16;
            float hec = he[cbase + c16];
            int ci = cbase + c16;
#pragma unroll
            for (int rt = 0; rt < 2; ++rt) {
                f32x4 acc = {0.f, 0.f, 0.f, 0.f};
                acc = __builtin_amdgcn_mfma_f32_16x16x32_bf16(ah[rt][0], bh[0], acc, 0, 0, 0);
                acc = __builtin_amdgcn_mfma_f32_16x16x32_bf16(ah[rt][1], bh[1], acc, 0, 0, 0);
                acc = __builtin_amdgcn_mfma_f32_16x16x32_bf16(ah[rt][0], bl[0], acc, 0, 0, 0);
                acc = __builtin_amdgcn_mfma_f32_16x16x32_bf16(ah[rt][1], bl[1], acc, 0, 0, 0);
                acc = __builtin_amdgcn_mfma_f32_16x16x32_bf16(al[rt][0], bh[0], acc, 0, 0, 0);
                acc = __builtin_amdgcn_mfma_f32_16x16x32_bf16(al[rt][1], bh[1], acc, 0, 0, 0);
                acc = __builtin_amdgcn_mfma_f32_16x16x32_bf16(al[rt][0], bl[0], acc, 0, 0, 0);
                acc = __builtin_amdgcn_mfma_f32_16x16x32_bf16(al[rt][1], bl[1], acc, 0, 0, 0);
#pragma unroll
                for (int r = 0; r < 4; ++r) {
                    float d = hec - acc[r];
                    int e = rt * 4 + r;
                    m2[e] = fminf(m2[e], fmaxf(d, m1[e]));
                    bool lt = d < m1[e];
                    i1[e] = lt ? ci : i1[e];
                    m1[e] = fminf(m1[e], d);
                }
            }
        }
        __syncthreads();
    }
#pragma unroll
    for (int m = 1; m < 16; m <<= 1) {
#pragma unroll
        for (int e = 0; e < 8; ++e) {
            float om1 = __shfl_xor(m1[e], m);
            float om2 = __shfl_xor(m2[e], m);
            int oi = __shfl_xor(i1[e], m);
            float nm2 = fminf(fminf(m2[e], om2), fmaxf(m1[e], om1));
            bool take = (om1 < m1[e]) || (om1 == m1[e] && oi < i1[e]);
            i1[e] = take ? oi : i1[e];
            m1[e] = fminf(m1[e], om1);
            m2[e] = nm2;
        }
    }
    if (c16 == 0) {
#pragma unroll
        for (int e = 0; e < 8; ++e) {
            int row = (int)R0 + w * 32 + (e >> 2) * 16 + q * 4 + (e & 3);
            idx[row] = i1[e];
            if (m2[e] - m1[e] < BAND) {
                int p = atomicAdd(&wl_cnt, 1);
                wl_rows[p] = row;
            }
        }
    }
    __syncthreads();
    if (tid == 0 && wl_cnt > 0) wl_base = atomicAdd(wcount, wl_cnt);
    __syncthreads();
    for (int i = tid; i < wl_cnt; i += 256) wlist[wl_base + i] = wl_rows[i];
}

// ---- K1b: exact fp32 rescan, one WAVE per worklist row (unchanged) ----
__global__ __launch_bounds__(256) void k_recheck(
    const float* __restrict__ x, const float* __restrict__ emb,
    const float* __restrict__ he, const int* __restrict__ wlist,
    const int* __restrict__ wcount, int* __restrict__ idx) {
    int lane = threadIdx.x & 63;
    int wave = (blockIdx.x * 256 + threadIdx.x) >> 6;
    int nwaves = (gridDim.x * 256) >> 6;
    int cnt = wcount[0];
    for (int i = wave; i < cnt; i += nwaves) {
        int row = wlist[i];
        const v4f* xr = (const v4f*)(x + (size_t)row * D);
        v4f X[16];
#pragma unroll
        for (int t = 0; t < 16; ++t) X[t] = xr[t];
        float bd = 3.4e38f; int bi = 0x7fffffff;
#pragma unroll
        for (int j = 0; j < 8; ++j) {
            int c = j * 64 + lane;
            const v4f* er = (const v4f*)(emb + (size_t)c * D);
            v4f s = X[0] * er[0];
#pragma unroll
            for (int t = 1; t < 16; ++t) s += X[t] * er[t];
            float dot = (s.x + s.y) + (s.z + s.w);
            float d = he[c] - dot;
            if (d < bd) { bd = d; bi = c; }
        }
#pragma unroll
        for (int m = 1; m < 64; m <<= 1) {
            float od = __shfl_xor(bd, m);
            int oi = __shfl_xor(bi, m);
            if (od < bd || (od == bd && oi < bi)) { bd = od; bi = oi; }
        }
        if (lane == 0) idx[row] = bi;
    }
}

// ---- K2a: per-block histogram (unchanged) ----
__global__ __launch_bounds__(256) void k_hist(const int* __restrict__ idx,
                                              float* __restrict__ gcount) {
    __shared__ int hist[KC];
    int tid = threadIdx.x;
    for (int i = tid; i < KC; i += 256) hist[i] = 0;
    __syncthreads();
    int base = blockIdx.x * HROWS;
    for (int r = base + tid; r < base + HROWS; r += 256)
        atomicAdd(&hist[idx[r]], 1);
    __syncthreads();
    for (int i = tid; i < KC; i += 256)
        gcount[(size_t)blockIdx.x * KC + i] = (float)hist[i];
}

// ---- K2b: segment sums as MFMA one-hot matmul: new_sum = P^T X ----
// 256 blocks x 1024 rows. 8 waves; wave w owns clusters [w*64, w*64+64)
// (4 k-tiles) x 4 d-tiles, acc in MFMA regs -> ZERO atomics.
// x chunk (32 rows) staged as packed (bf16hi | bf16lo<<16) dwords, rotated
// (d+2n)&63 so both staging writes and per-lane gathers are ~conflict-free.
// A = one-hot from idx (exact in bf16); hi+lo MFMA pair -> fp32-exact sums.
__global__ __launch_bounds__(512, 1) void k_segsum(
    const float* __restrict__ x, const int* __restrict__ idx,
    float* __restrict__ gpart) {
    __shared__ int sidx[SROWS];        // 4 KB
    __shared__ unsigned xpk[32 * 64];  // 8 KB
    int tid = threadIdx.x;
    int lane = tid & 63, w = tid >> 6, q = lane >> 4, c16 = lane & 15;
    int nb0 = blockIdx.x * SROWS;
    for (int i = tid; i < SROWS; i += 512) sidx[i] = idx[nb0 + i];

    f32x4 acc[4][4];
#pragma unroll
    for (int a = 0; a < 4; ++a)
#pragma unroll
        for (int b = 0; b < 4; ++b) acc[a][b] = (f32x4){0.f, 0.f, 0.f, 0.f};

    int row32 = tid >> 4, d4 = tid & 15;
    for (int ch = 0; ch < SROWS / 32; ++ch) {
        __syncthreads();  // protects sidx (ch=0) and xpk reuse (ch>0)
        float4 v = ((const float4*)(x + (size_t)(nb0 + ch * 32 + row32) * D))[d4];
        float vals[4] = {v.x, v.y, v.z, v.w};
#pragma unroll
        for (int i = 0; i < 4; ++i) {
            unsigned short h = bf16_rne(vals[i]);
            unsigned short l = bf16_rne(vals[i] - bf16_f(h));
            int d = d4 * 4 + i;
            xpk[row32 * 64 + ((d + 2 * row32) & 63)] =
                (unsigned)h | ((unsigned)l << 16);
        }
        __syncthreads();

        int iv[8];
#pragma unroll
        for (int j = 0; j < 8; ++j) iv[j] = sidx[ch * 32 + q * 8 + j];
        s8v af[4];
#pragma unroll
        for (int kt = 0; kt < 4; ++kt) {
            int tgt = w * 64 + kt * 16 + c16;
#pragma unroll
            for (int j = 0; j < 8; ++j)
                af[kt][j] = (iv[j] == tgt) ? (short)0x3F80 : (short)0;
        }
#pragma unroll
        for (int dt = 0; dt < 4; ++dt) {
            s8v bh, bl;
#pragma unroll
            for (int j = 0; j < 8; ++j) {
                int n32 = q * 8 + j;
                unsigned pv = xpk[n32 * 64 + ((dt * 16 + c16 + 2 * n32) & 63)];
                bh[j] = (short)(pv & 0xffff);
                bl[j] = (short)(pv >> 16);
            }
#pragma unroll
            for (int kt = 0; kt < 4; ++kt) {
                acc[kt][dt] = __builtin_amdgcn_mfma_f32_16x16x32_bf16(af[kt], bh, acc[kt][dt], 0, 0, 0);
                acc[kt][dt] = __builtin_amdgcn_mfma_f32_16x16x32_bf16(af[kt], bl, acc[kt][dt], 0, 0, 0);
            }
        }
    }
    // C-layout: col=lane&15, row=q*4+reg -> gpart[b][k][d]
    float* gp = gpart + (size_t)blockIdx.x * (KC * D);
#pragma unroll
    for (int kt = 0; kt < 4; ++kt)
#pragma unroll
        for (int dt = 0; dt < 4; ++dt)
#pragma unroll
            for (int r = 0; r < 4; ++r) {
                int k = w * 64 + kt * 16 + q * 4 + r;
                gp[k * D + dt * 16 + c16] = acc[kt][dt][r];
            }
}

// ---- K3: fused reduce(gpart) + reduce(gcount) + EMA (unchanged) ----
__global__ __launch_bounds__(256) void k_final(
    const float* __restrict__ gpart, const float* __restrict__ gcount,
    const float* __restrict__ cnt_in, const float* __restrict__ sum_embed,
    float* __restrict__ embnew) {
    __shared__ float cs[4];
    int tid = threadIdx.x;
    int i = blockIdx.x * 256 + tid;
    float s = 0.f;
#pragma unroll 4
    for (int c = 0; c < NCHUNK; ++c) s += gpart[(size_t)c * (KC * D) + i];
    if ((tid & 63) == 0) {
        int k = i >> 6;
        float c = 0.f;
#pragma unroll 4
        for (int b = 0; b < NHB; ++b) c += gcount[(size_t)b * KC + k];
        cs[tid >> 6] = c;
    }
    __syncthreads();
    float c = cs[tid >> 6];
    float c0 = cnt_in[i >> 6];
    float cn = c0 + EMA_A * (c - c0);
    float se0 = sum_embed[i];
    float se = se0 + EMA_A * (s - se0);
    embnew[i] = (cn >= 1.0f) ? (se / cn) : 0.0f;
}

// ---- K4: gather (unchanged) ----
__global__ __launch_bounds__(256) void k_gather(const int* __restrict__ idx,
                                                const float* __restrict__ embnew,
                                                float* __restrict__ out, int N) {
    int g = blockIdx.x * 256 + threadIdx.x;
    int row = g >> 4, q = g & 15;
    if (row >= N) return;
    int k = idx[row];
    const float4* e4 = (const float4*)embnew;
    ((float4*)out)[(size_t)row * (D / 4) + q] = e4[k * (D / 4) + q];
}

extern "C" void kernel_launch(void* const* d_in, const int* in_sizes, int n_in,
                              void* d_out, int out_size, void* d_ws, size_t ws_size,
                              hipStream_t stream) {
    const float* x = (const float*)d_in[0];
    const float* emb = (const float*)d_in[1];
    const float* cnt = (const float*)d_in[2];
    const float* sum_embed = (const float*)d_in[3];
    float* out = (float*)d_out;
    int N = in_sizes[0] / D;  // 262144

    char* w = (char*)d_ws;
    size_t off = 0;
    int* idx = (int*)(w + off);        off += (size_t)N * 4;
    int* wlist = (int*)(w + off);      off += (size_t)N * 4;
    int* wcount = (int*)(w + off);     off += 16;
    float* he = (float*)(w + off);     off += (size_t)KC * 4;
    short* gB = (short*)(w + off);     off += (size_t)8 * 8192 * 2;  // 128 KB
    float* embnew = (float*)(w + off); off += (size_t)KC * D * 4;
    float* gcount = (float*)(w + off); off += (size_t)NHB * KC * 4;
    float* gpart = (float*)(w + off);  off += (size_t)NCHUNK * KC * D * 4;

    k_prep<<<(KC + 255) / 256, 256, 0, stream>>>(emb, he, gB, wcount);
    k_assign<<<N / 128, 256, 0, stream>>>(x, gB, he, idx, wlist, wcount);
    k_recheck<<<512, 256, 0, stream>>>(x, emb, he, wlist, wcount, idx);
    k_hist<<<NHB, 256, 0, stream>>>(idx, gcount);
    k_segsum<<<NCHUNK, 512, 0, stream>>>(x, idx, gpart);
    k_final<<<(KC * D) / 256, 256, 0, stream>>>(gpart, gcount, cnt, sum_embed, embnew);
    k_gather<<<((size_t)N * (D / 4)) / 256, 256, 0, stream>>>(idx, embnew, out, N);
}

// Round 9
// 313.846 us; speedup vs baseline: 1.4061x; 1.0232x over previous
//
#include <hip/hip_runtime.h>

#define D 64
#define KC 512
#define EMA_A 0.01f
#define SROWS 1024     // rows per segsum block
#define NCHUNK 256     // N / SROWS (gpart + gcount partials)
#define BAND 0.0078125f // recheck band; 4-term split error <~5e-4 -> 16x margin

typedef float f32x4 __attribute__((ext_vector_type(4)));
typedef float v4f __attribute__((ext_vector_type(4)));
typedef short s8v __attribute__((ext_vector_type(8)));   // 8 bf16 as shorts
typedef short s4v __attribute__((ext_vector_type(4)));

__device__ inline unsigned short bf16_rne(float f) {
    unsigned u = __float_as_uint(f);
    return (unsigned short)((u + 0x7fffu + ((u >> 16) & 1u)) >> 16);
}
__device__ inline float bf16_f(unsigned short h) {
    return __uint_as_float(((unsigned)h) << 16);
}

// ---- K0: he[k] = 0.5*||emb_k||^2 ; pre-swizzled bf16 hi/lo B images ;
//          zero recheck worklist count ----
__global__ __launch_bounds__(256) void k_prep(const float* __restrict__ emb,
                                              float* __restrict__ he,
                                              short* __restrict__ gB,
                                              int* __restrict__ wcount) {
    if (blockIdx.x == 0 && threadIdx.x == 0) wcount[0] = 0;
    int k = blockIdx.x * 256 + threadIdx.x;
    if (k >= KC) return;
    int c8 = k >> 6, c = k & 63;
    short* dst = gB + (size_t)c8 * 8192;
    float s = 0.f;
#pragma unroll
    for (int kq = 0; kq < 16; ++kq) {
        float4 v = ((const float4*)(emb + (size_t)k * D))[kq];
        s = fmaf(v.x, v.x, s); s = fmaf(v.y, v.y, s);
        s = fmaf(v.z, v.z, s); s = fmaf(v.w, v.w, s);
        unsigned short h0 = bf16_rne(v.x), h1 = bf16_rne(v.y);
        unsigned short h2 = bf16_rne(v.z), h3 = bf16_rne(v.w);
        s4v hv = {(short)h0, (short)h1, (short)h2, (short)h3};
        s4v lv = {(short)bf16_rne(v.x - bf16_f(h0)),
                  (short)bf16_rne(v.y - bf16_f(h1)),
                  (short)bf16_rne(v.z - bf16_f(h2)),
                  (short)bf16_rne(v.w - bf16_f(h3))};
        int si = c * 64 + (((kq >> 1) ^ (c & 7)) * 8) + (kq & 1) * 4;
        *(s4v*)(&dst[si]) = hv;
        *(s4v*)(&dst[4096 + si]) = lv;
    }
    he[k] = 0.5f * s;
}

// ---- K1: MFMA 4-term split-bf16 argmin, occupancy-optimized.
// 512 thr / 8 waves / 128 rows per block; 16 rows per wave -> A frags 16
// VGPR, min-state 12 -> fits 85-reg cap -> 3 blocks/CU (24 waves, 75%).
// Single 16KB LDS buffer: A staged hi then lo (lo kept in regs across the
// barrier), then B chunks stream through. 2 independent 4-MFMA chains.
__global__ __launch_bounds__(512, 6) void k_assign(
    const float* __restrict__ x, const short* __restrict__ gB,
    const float* __restrict__ he, int* __restrict__ idx,
    int* __restrict__ wlist, int* __restrict__ wcount) {
    __shared__ __align__(16) short LB[8192];  // 16 KB
    __shared__ int wl_cnt, wl_base;
    __shared__ int wl_rows[128];
    int tid = threadIdx.x;
    int lane = tid & 63, w = tid >> 6, q = lane >> 4, c16 = lane & 15;
    size_t R0 = (size_t)blockIdx.x * 128;
    if (tid == 0) wl_cnt = 0;

    // A pass 1: hi image to LDS, lo kept in regs
    const float4* xg = (const float4*)(x + R0 * D);
    s4v lo_keep[4];
#pragma unroll
    for (int p = 0; p < 4; ++p) {
        int flat = p * 512 + tid;
        int row = flat >> 4, kq = flat & 15;
        float4 v = xg[flat];
        unsigned short h0 = bf16_rne(v.x), h1 = bf16_rne(v.y);
        unsigned short h2 = bf16_rne(v.z), h3 = bf16_rne(v.w);
        s4v hv = {(short)h0, (short)h1, (short)h2, (short)h3};
        lo_keep[p] = (s4v){(short)bf16_rne(v.x - bf16_f(h0)),
                           (short)bf16_rne(v.y - bf16_f(h1)),
                           (short)bf16_rne(v.z - bf16_f(h2)),
                           (short)bf16_rne(v.w - bf16_f(h3))};
        int si = row * 64 + (((kq >> 1) ^ (row & 7)) * 8) + (kq & 1) * 4;
        *(s4v*)(&LB[si]) = hv;
    }
    __syncthreads();
    s8v ah[2], al[2];
    {
        int row = w * 16 + c16;
#pragma unroll
        for (int ks = 0; ks < 2; ++ks) {
            int kb = (ks * 4 + q) ^ (row & 7);
            ah[ks] = *(const s8v*)(&LB[row * 64 + kb * 8]);
        }
    }
    __syncthreads();
    // A pass 2: lo image
#pragma unroll
    for (int p = 0; p < 4; ++p) {
        int flat = p * 512 + tid;
        int row = flat >> 4, kq = flat & 15;
        int si = row * 64 + (((kq >> 1) ^ (row & 7)) * 8) + (kq & 1) * 4;
        *(s4v*)(&LB[si]) = lo_keep[p];
    }
    __syncthreads();
    {
        int row = w * 16 + c16;
#pragma unroll
        for (int ks = 0; ks < 2; ++ks) {
            int kb = (ks * 4 + q) ^ (row & 7);
            al[ks] = *(const s8v*)(&LB[row * 64 + kb * 8]);
        }
    }

    float m1[4], m2[4]; int i1[4];
#pragma unroll
    for (int e = 0; e < 4; ++e) { m1[e] = 3.4e38f; m2[e] = 3.4e38f; i1[e] = 0; }

    for (int c8 = 0; c8 < 8; ++c8) {
        __syncthreads();  // prev readers done (covers al read for c8=0)
        const int4* src = (const int4*)(gB + (size_t)c8 * 8192);
        ((int4*)LB)[tid] = src[tid];
        ((int4*)LB)[512 + tid] = src[512 + tid];
        __syncthreads();
#pragma unroll
        for (int ct = 0; ct < 4; ++ct) {
            s8v bh[2], bl[2];
#pragma unroll
            for (int ks = 0; ks < 2; ++ks) {
                int c = ct * 16 + c16;
                int kb = (ks * 4 + q) ^ (c & 7);
                bh[ks] = *(const s8v*)(&LB[c * 64 + kb * 8]);
                bl[ks] = *(const s8v*)(&LB[4096 + c * 64 + kb * 8]);
            }
            int cbase = c8 * 64 + ct * 16;
            float hec = he[cbase + c16];
            int ci = cbase + c16;
            f32x4 a0 = {0.f, 0.f, 0.f, 0.f}, a1 = {0.f, 0.f, 0.f, 0.f};
            a0 = __builtin_amdgcn_mfma_f32_16x16x32_bf16(ah[0], bh[0], a0, 0, 0, 0);
            a0 = __builtin_amdgcn_mfma_f32_16x16x32_bf16(ah[1], bh[1], a0, 0, 0, 0);
            a0 = __builtin_amdgcn_mfma_f32_16x16x32_bf16(ah[0], bl[0], a0, 0, 0, 0);
            a0 = __builtin_amdgcn_mfma_f32_16x16x32_bf16(ah[1], bl[1], a0, 0, 0, 0);
            a1 = __builtin_amdgcn_mfma_f32_16x16x32_bf16(al[0], bh[0], a1, 0, 0, 0);
            a1 = __builtin_amdgcn_mfma_f32_16x16x32_bf16(al[1], bh[1], a1, 0, 0, 0);
            a1 = __builtin_amdgcn_mfma_f32_16x16x32_bf16(al[0], bl[0], a1, 0, 0, 0);
            a1 = __builtin_amdgcn_mfma_f32_16x16x32_bf16(al[1], bl[1], a1, 0, 0, 0);
#pragma unroll
            for (int r = 0; r < 4; ++r) {
                float d = (hec - a0[r]) - a1[r];
                m2[r] = fminf(m2[r], fmaxf(d, m1[r]));  // before m1 update
                bool lt = d < m1[r];                    // strict: first-min
                i1[r] = lt ? ci : i1[r];
                m1[r] = fminf(m1[r], d);
            }
        }
    }
    // reduce (m1,i1,m2) across the 16 lanes of each quad group
#pragma unroll
    for (int m = 1; m < 16; m <<= 1) {
#pragma unroll
        for (int e = 0; e < 4; ++e) {
            float om1 = __shfl_xor(m1[e], m);
            float om2 = __shfl_xor(m2[e], m);
            int oi = __shfl_xor(i1[e], m);
            float nm2 = fminf(fminf(m2[e], om2), fmaxf(m1[e], om1));
            bool take = (om1 < m1[e]) || (om1 == m1[e] && oi < i1[e]);
            i1[e] = take ? oi : i1[e];
            m1[e] = fminf(m1[e], om1);
            m2[e] = nm2;
        }
    }
    if (c16 == 0) {
#pragma unroll
        for (int e = 0; e < 4; ++e) {
            int row = (int)R0 + w * 16 + q * 4 + e;
            idx[row] = i1[e];
            if (m2[e] - m1[e] < BAND) {
                int p = atomicAdd(&wl_cnt, 1);   // LDS atomic
                wl_rows[p] = row;
            }
        }
    }
    __syncthreads();
    if (tid == 0 && wl_cnt > 0) wl_base = atomicAdd(wcount, wl_cnt);
    __syncthreads();
    for (int i = tid; i < wl_cnt; i += 512) wlist[wl_base + i] = wl_rows[i];
}

// ---- K1b: exact fp32 rescan, one WAVE per worklist row (unchanged) ----
__global__ __launch_bounds__(256) void k_recheck(
    const float* __restrict__ x, const float* __restrict__ emb,
    const float* __restrict__ he, const int* __restrict__ wlist,
    const int* __restrict__ wcount, int* __restrict__ idx) {
    int lane = threadIdx.x & 63;
    int wave = (blockIdx.x * 256 + threadIdx.x) >> 6;
    int nwaves = (gridDim.x * 256) >> 6;
    int cnt = wcount[0];
    for (int i = wave; i < cnt; i += nwaves) {
        int row = wlist[i];
        const v4f* xr = (const v4f*)(x + (size_t)row * D);
        v4f X[16];
#pragma unroll
        for (int t = 0; t < 16; ++t) X[t] = xr[t];
        float bd = 3.4e38f; int bi = 0x7fffffff;
#pragma unroll
        for (int j = 0; j < 8; ++j) {
            int c = j * 64 + lane;
            const v4f* er = (const v4f*)(emb + (size_t)c * D);
            v4f s = X[0] * er[0];
#pragma unroll
            for (int t = 1; t < 16; ++t) s += X[t] * er[t];
            float dot = (s.x + s.y) + (s.z + s.w);
            float d = he[c] - dot;
            if (d < bd) { bd = d; bi = c; }
        }
#pragma unroll
        for (int m = 1; m < 64; m <<= 1) {
            float od = __shfl_xor(bd, m);
            int oi = __shfl_xor(bi, m);
            if (od < bd || (od == bd && oi < bi)) { bd = od; bi = oi; }
        }
        if (lane == 0) idx[row] = bi;
    }
}

// ---- K2: MFMA one-hot segment sums + FUSED count histogram ----
// 64-row x staging (barriers 64 -> 34); hist over LDS while sidx is hot.
__global__ __launch_bounds__(512, 1) void k_segsum(
    const float* __restrict__ x, const int* __restrict__ idx,
    float* __restrict__ gpart, float* __restrict__ gcount) {
    __shared__ int sidx[SROWS];          // 4 KB
    __shared__ unsigned xpk[64 * 64];    // 16 KB
    __shared__ int hist[KC];             // 2 KB
    int tid = threadIdx.x;
    int lane = tid & 63, w = tid >> 6, q = lane >> 4, c16 = lane & 15;
    int nb0 = blockIdx.x * SROWS;
    for (int i = tid; i < SROWS; i += 512) sidx[i] = idx[nb0 + i];
    hist[tid] = 0;   // blockDim == KC == 512
    __syncthreads();
    for (int i = tid; i < SROWS; i += 512) atomicAdd(&hist[sidx[i]], 1);

    f32x4 acc[4][4];
#pragma unroll
    for (int a = 0; a < 4; ++a)
#pragma unroll
        for (int b = 0; b < 4; ++b) acc[a][b] = (f32x4){0.f, 0.f, 0.f, 0.f};

    for (int ch = 0; ch < SROWS / 64; ++ch) {
        __syncthreads();  // xpk reuse (and hist atomics done by first iter)
#pragma unroll
        for (int pp = 0; pp < 2; ++pp) {
            int flat = pp * 512 + tid;
            int r64 = flat >> 4, d4 = flat & 15;
            float4 v = ((const float4*)(x + (size_t)(nb0 + ch * 64 + r64) * D))[d4];
            float vals[4] = {v.x, v.y, v.z, v.w};
#pragma unroll
            for (int i = 0; i < 4; ++i) {
                unsigned short h = bf16_rne(vals[i]);
                unsigned short l = bf16_rne(vals[i] - bf16_f(h));
                int d = d4 * 4 + i;
                xpk[r64 * 64 + ((d + 2 * r64) & 63)] =
                    (unsigned)h | ((unsigned)l << 16);
            }
        }
        __syncthreads();
#pragma unroll
        for (int s = 0; s < 2; ++s) {
            int iv[8];
#pragma unroll
            for (int j = 0; j < 8; ++j)
                iv[j] = sidx[ch * 64 + s * 32 + q * 8 + j];
            s8v af[4];
#pragma unroll
            for (int kt = 0; kt < 4; ++kt) {
                int tgt = w * 64 + kt * 16 + c16;
#pragma unroll
                for (int j = 0; j < 8; ++j)
                    af[kt][j] = (iv[j] == tgt) ? (short)0x3F80 : (short)0;
            }
#pragma unroll
            for (int dt = 0; dt < 4; ++dt) {
                s8v bh, bl;
#pragma unroll
                for (int j = 0; j < 8; ++j) {
                    int n = s * 32 + q * 8 + j;
                    unsigned pv = xpk[n * 64 + ((dt * 16 + c16 + 2 * n) & 63)];
                    bh[j] = (short)(pv & 0xffff);
                    bl[j] = (short)(pv >> 16);
                }
#pragma unroll
                for (int kt = 0; kt < 4; ++kt) {
                    acc[kt][dt] = __builtin_amdgcn_mfma_f32_16x16x32_bf16(af[kt], bh, acc[kt][dt], 0, 0, 0);
                    acc[kt][dt] = __builtin_amdgcn_mfma_f32_16x16x32_bf16(af[kt], bl, acc[kt][dt], 0, 0, 0);
                }
            }
        }
    }
    float* gp = gpart + (size_t)blockIdx.x * (KC * D);
#pragma unroll
    for (int kt = 0; kt < 4; ++kt)
#pragma unroll
        for (int dt = 0; dt < 4; ++dt)
#pragma unroll
            for (int r = 0; r < 4; ++r) {
                int k = w * 64 + kt * 16 + q * 4 + r;
                gp[k * D + dt * 16 + c16] = acc[kt][dt][r];
            }
    __syncthreads();
    gcount[(size_t)blockIdx.x * KC + tid] = (float)hist[tid];
}

// ---- K3: one block per cluster: reduce gpart+gcount + EMA -> embedding_new --
// usage==0 clusters never appear in encoding_index -> flat[r] path is dead.
__global__ __launch_bounds__(256) void k_final(
    const float* __restrict__ gpart, const float* __restrict__ gcount,
    const float* __restrict__ cnt_in, const float* __restrict__ sum_embed,
    float* __restrict__ embnew) {
    __shared__ float sp[4][64];
    __shared__ float cp[256];
    int k = blockIdx.x;               // 512 blocks = KC
    int tid = threadIdx.x;
    int d = tid & 63, g = tid >> 6;
    float s = 0.f;
    for (int c = g * 64; c < g * 64 + 64; ++c)
        s += gpart[(size_t)c * (KC * D) + k * D + d];
    sp[g][d] = s;
    cp[tid] = gcount[(size_t)tid * KC + k];
    __syncthreads();
    if (g == 0) {
        float st = sp[0][d] + sp[1][d] + sp[2][d] + sp[3][d];
        float cv = cp[4 * d] + cp[4 * d + 1] + cp[4 * d + 2] + cp[4 * d + 3];
#pragma unroll
        for (int m = 1; m < 64; m <<= 1) cv += __shfl_xor(cv, m);
        float c0 = cnt_in[k];
        float cn = c0 + EMA_A * (cv - c0);
        float se0 = sum_embed[k * D + d];
        float se = se0 + EMA_A * (st - se0);
        embnew[k * D + d] = (cn >= 1.0f) ? (se / cn) : 0.0f;
    }
}

// ---- K4: gather out[n][:] = embnew[idx[n]][:] ----
__global__ __launch_bounds__(256) void k_gather(const int* __restrict__ idx,
                                                const float* __restrict__ embnew,
                                                float* __restrict__ out, int N) {
    int g = blockIdx.x * 256 + threadIdx.x;
    int row = g >> 4, q = g & 15;
    if (row >= N) return;
    int k = idx[row];
    const float4* e4 = (const float4*)embnew;
    ((float4*)out)[(size_t)row * (D / 4) + q] = e4[k * (D / 4) + q];
}

extern "C" void kernel_launch(void* const* d_in, const int* in_sizes, int n_in,
                              void* d_out, int out_size, void* d_ws, size_t ws_size,
                              hipStream_t stream) {
    const float* x = (const float*)d_in[0];
    const float* emb = (const float*)d_in[1];
    const float* cnt = (const float*)d_in[2];
    const float* sum_embed = (const float*)d_in[3];
    float* out = (float*)d_out;
    int N = in_sizes[0] / D;  // 262144

    char* w = (char*)d_ws;
    size_t off = 0;
    int* idx = (int*)(w + off);        off += (size_t)N * 4;
    int* wlist = (int*)(w + off);      off += (size_t)N * 4;
    int* wcount = (int*)(w + off);     off += 16;
    float* he = (float*)(w + off);     off += (size_t)KC * 4;
    short* gB = (short*)(w + off);     off += (size_t)8 * 8192 * 2;  // 128 KB
    float* embnew = (float*)(w + off); off += (size_t)KC * D * 4;
    float* gcount = (float*)(w + off); off += (size_t)NCHUNK * KC * 4;
    float* gpart = (float*)(w + off);  off += (size_t)NCHUNK * KC * D * 4;

    k_prep<<<(KC + 255) / 256, 256, 0, stream>>>(emb, he, gB, wcount);
    k_assign<<<N / 128, 512, 0, stream>>>(x, gB, he, idx, wlist, wcount);
    k_recheck<<<512, 256, 0, stream>>>(x, emb, he, wlist, wcount, idx);
    k_segsum<<<NCHUNK, 512, 0, stream>>>(x, idx, gpart, gcount);
    k_final<<<KC, 256, 0, stream>>>(gpart, gcount, cnt, sum_embed, embnew);
    k_gather<<<((size_t)N * (D / 4)) / 256, 256, 0, stream>>>(idx, embnew, out, N);
}